// Round 11
// baseline (302.192 us; speedup 1.0000x reference)
//
#include <hip/hip_runtime.h>

// NW=32 wavelets, N=M=1024.
#define NPOINTS 1048576ULL
#define NWV 32
#define ZSTR 40   // h16 stride of [k1][n2] Z planes (16B-aligned rows)
#define PSTR 33   // u32 stride of stage plane [n2][n1] (odd -> <=2-way banks)

typedef _Float16 h8 __attribute__((ext_vector_type(8)));
typedef _Float16 h2 __attribute__((ext_vector_type(2)));
typedef short    s8v __attribute__((ext_vector_type(8)));
typedef float    f32x4 __attribute__((ext_vector_type(4)));

// Scaling plan (rounds 3-10): no 1/(N*M) in the FFTs; conv' = 2^20*conv.
// mod' = sqrt(|conv'|^2 + 1e-8*2^40); final scale 2^-60 in k_reduce.

__device__ __forceinline__ f32x4 MF(h8 a, h8 b, f32x4 c) {
    return __builtin_amdgcn_mfma_f32_16x16x32_f16(a, b, c, 0, 0, 0);
}
__device__ __forceinline__ h8 hneg(h8 x) {
    s8v s = *(s8v*)&x;
    s = s ^ (short)0x8000;
    return *(h8*)&s;
}
// sin/cos of (2*pi*rev): hardware trans ops take REVOLUTIONS (cdna4_isa §3).
__device__ __forceinline__ float fsin_rev(float rev) {
    float r; asm("v_sin_f32 %0, %1" : "=v"(r) : "v"(rev)); return r;
}
__device__ __forceinline__ float fcos_rev(float rev) {
    float r; asm("v_cos_f32 %0, %1" : "=v"(r) : "v"(rev)); return r;
}

// Per-lane F32 fragments (built ONCE per kernel, reused every FFT).
__device__ __forceinline__ void build_ffrags(int g, int c16,
    h8& fr0, h8& fi0, h8& fr1, h8& fi1)
{
    #pragma unroll
    for (int j = 0; j < 8; ++j) {
        int b = 8 * g + j;
        float r0 = (float)((c16 * b) & 31) * (1.0f / 32.0f);
        float r1 = (float)(((16 + c16) * b) & 31) * (1.0f / 32.0f);
        fr0[j] = (_Float16)fcos_rev(r0); fi0[j] = (_Float16)fsin_rev(r0);
        fr1[j] = (_Float16)fcos_rev(r1); fi1[j] = (_Float16)fsin_rev(r1);
    }
}

// Per-lane TW twiddles W1024^(n2*k1) for the 16 (quadrant,rp,A/B) slots —
// built ONCE, all-literal indexing -> stays in VGPRs (32 regs).
__device__ __forceinline__ void build_tw(int g, int c16, float2* tw) {
    #pragma unroll
    for (int qi = 0; qi < 2; ++qi)
        #pragma unroll
        for (int qj = 0; qj < 2; ++qj)
            #pragma unroll
            for (int rp = 0; rp < 2; ++rp) {
                const int k1 = 16 * qj + c16;
                const int n2 = 16 * qi + 4 * g + 2 * rp;
                const int idx = qi * 8 + qj * 4 + rp * 2;
                float rA = (float)(n2 * k1) * (1.0f / 1024.0f);
                float rB = (float)((n2 + 1) * k1) * (1.0f / 1024.0f);
                tw[idx]     = make_float2(fcos_rev(rA), fsin_rev(rA));
                tw[idx + 1] = make_float2(fcos_rev(rB), fsin_rev(rB));
            }
}

// Unpack staged u32 (h2{re,im}) plane into MFMA A-fragments.
__device__ __forceinline__ void load_frags(const unsigned int* __restrict__ pl,
    int g, int c16, h8& ar0, h8& ai0, h8& ar1, h8& ai1)
{
    #pragma unroll
    for (int j = 0; j < 8; ++j) {
        unsigned int v0 = pl[PSTR * c16 + 8 * g + j];
        unsigned int v1 = pl[PSTR * (16 + c16) + 8 * g + j];
        h2 p0 = *(h2*)&v0, p1 = *(h2*)&v1;
        ar0[j] = p0.x; ai0[j] = p0.y;
        ar1[j] = p1.x; ai1[j] = p1.y;
    }
}

struct EOut { f32x4 r00, r01, r10, r11, i00, i01, i10, i11; };

// 1024-pt inverse FFT per wave, four-step 32x32 (validated rounds 7-10);
// twiddles/F-fragments precomputed in registers.
__device__ __forceinline__ EOut fft_core(
    h8 ar0, h8 ai0, h8 ar1, h8 ai1,
    h8 fr0, h8 fr1, h8 fi0, h8 fi1, h8 mfi0, h8 mfi1,
    const float2* __restrict__ tw,
    _Float16* __restrict__ Zr, _Float16* __restrict__ Zi,
    int g, int c16)
{
    const f32x4 z = {0.f, 0.f, 0.f, 0.f};
    f32x4 dr00=z, dr01=z, dr10=z, dr11=z, di00=z, di01=z, di10=z, di11=z;
    dr00 = MF(ar0, fr0, dr00); dr00 = MF(ai0, mfi0, dr00);
    di00 = MF(ar0, fi0, di00); di00 = MF(ai0, fr0,  di00);
    dr01 = MF(ar0, fr1, dr01); dr01 = MF(ai0, mfi1, dr01);
    di01 = MF(ar0, fi1, di01); di01 = MF(ai0, fr1,  di01);
    dr10 = MF(ar1, fr0, dr10); dr10 = MF(ai1, mfi0, dr10);
    di10 = MF(ar1, fi0, di10); di10 = MF(ai1, fr0,  di10);
    dr11 = MF(ar1, fr1, dr11); dr11 = MF(ai1, mfi1, dr11);
    di11 = MF(ar1, fi1, di11); di11 = MF(ai1, fr1,  di11);

#define TWZ(DR, DI, QI, QJ)                                                    \
    {                                                                          \
        const int k1 = 16 * (QJ) + c16;                                        \
        _Pragma("unroll")                                                      \
        for (int rp = 0; rp < 2; ++rp) {                                       \
            const int n2 = 16 * (QI) + 4 * g + 2 * rp;                         \
            float2 tA = tw[(QI) * 8 + (QJ) * 4 + rp * 2];                      \
            float2 tB = tw[(QI) * 8 + (QJ) * 4 + rp * 2 + 1];                  \
            float yr0 = DR[2*rp],   yi0 = DI[2*rp];                            \
            float yr1 = DR[2*rp+1], yi1 = DI[2*rp+1];                          \
            h2 zr2 = { (_Float16)(yr0*tA.x - yi0*tA.y),                        \
                       (_Float16)(yr1*tB.x - yi1*tB.y) };                      \
            h2 zi2 = { (_Float16)(yi0*tA.x + yr0*tA.y),                        \
                       (_Float16)(yi1*tB.x + yr1*tB.y) };                      \
            *(h2*)&Zr[k1 * ZSTR + n2] = zr2;                                   \
            *(h2*)&Zi[k1 * ZSTR + n2] = zi2;                                   \
        }                                                                      \
    }
    TWZ(dr00, di00, 0, 0) TWZ(dr01, di01, 0, 1)
    TWZ(dr10, di10, 1, 0) TWZ(dr11, di11, 1, 1)
#undef TWZ

    h8 a3r0 = *(h8*)&Zr[c16 * ZSTR + 8 * g];
    h8 a3i0 = *(h8*)&Zi[c16 * ZSTR + 8 * g];
    h8 a3r1 = *(h8*)&Zr[(16 + c16) * ZSTR + 8 * g];
    h8 a3i1 = *(h8*)&Zi[(16 + c16) * ZSTR + 8 * g];

    EOut e;
    e.r00 = MF(a3r0, fr0, z); e.r00 = MF(a3i0, mfi0, e.r00);
    e.i00 = MF(a3r0, fi0, z); e.i00 = MF(a3i0, fr0,  e.i00);
    e.r01 = MF(a3r0, fr1, z); e.r01 = MF(a3i0, mfi1, e.r01);
    e.i01 = MF(a3r0, fi1, z); e.i01 = MF(a3i0, fr1,  e.i01);
    e.r10 = MF(a3r1, fr0, z); e.r10 = MF(a3i1, mfi0, e.r10);
    e.i10 = MF(a3r1, fi0, z); e.i10 = MF(a3i1, fr0,  e.i10);
    e.r11 = MF(a3r1, fr1, z); e.r11 = MF(a3i1, mfi1, e.r11);
    e.i11 = MF(a3r1, fi1, z); e.i11 = MF(a3i1, fr1,  e.i11);
    return e;
}

// ---------------------------------------------------------------------------
// Pass A: 4 waves/block = 4 rows/iteration, ITER=4 iterations (trig built
// once, amortized 4x). Vectorized natural-order loads, cmul, LDS stage,
// MFMA FFT, block transpose, coalesced stores to T[nb][k][4n].
// ---------------------------------------------------------------------------
#define ITER 4
__global__ __launch_bounds__(256, 6) void k_rowfft(
    const float* __restrict__ xhat, const float* __restrict__ pre,
    const float* __restrict__ pim, unsigned int* __restrict__ T, int wbase)
{
    __shared__ unsigned int WSP[4][1312];   // per-wave stage/Z union; Ttile union
    const int t = threadIdx.x, wv = t >> 6, l = t & 63, g = l >> 4, c16 = l & 15;
    const int wl = blockIdx.y, w = wbase + wl;

    h8 fr0, fi0, fr1, fi1;
    build_ffrags(g, c16, fr0, fi0, fr1, fi1);
    h8 mfi0 = hneg(fi0), mfi1 = hneg(fi1);
    float2 tw[16];
    build_tw(g, c16, tw);

    unsigned int* pl = &WSP[wv][0];
    unsigned int* Ttile = &WSP[0][0];       // [k2]*132 + [k1]*4 + wv
    unsigned int* Tw = T + (size_t)wl * NPOINTS;
    const int n2b = 4 * (l & 7), n1b = l >> 3;

    for (int it = 0; it < ITER; ++it) {
        const int nb = blockIdx.x * ITER + it;
        const int n  = nb * 4 + wv;
        // Stage: m = 256c + 4l + i  ->  n1 = 8c + (l>>3), n2 = 4*(l&7) + i.
        const float4* pr4 = (const float4*)(pre + (size_t)w * NPOINTS + (size_t)n * 1024);
        const float4* pi4 = (const float4*)(pim + (size_t)w * NPOINTS + (size_t)n * 1024);
        const float4* xh4 = (const float4*)(xhat + (size_t)n * 2048);
        #pragma unroll
        for (int c = 0; c < 4; ++c) {
            float4 a  = pr4[64 * c + l];
            float4 b  = pi4[64 * c + l];
            float4 x0 = xh4[128 * c + 2 * l];
            float4 x1 = xh4[128 * c + 2 * l + 1];
            float xr[4] = {x0.x, x0.z, x1.x, x1.z};
            float xi[4] = {x0.y, x0.w, x1.y, x1.w};
            float pa[4] = {a.x, a.y, a.z, a.w};
            float pb[4] = {b.x, b.y, b.z, b.w};
            const int n1 = 8 * c + n1b;
            #pragma unroll
            for (int i = 0; i < 4; ++i) {
                float re = xr[i] * pa[i] - xi[i] * pb[i];
                float im = xi[i] * pa[i] + xr[i] * pb[i];
                h2 p = {(_Float16)re, (_Float16)im};
                pl[PSTR * (n2b + i) + n1] = *(unsigned int*)&p;
            }
        }
        h8 ar0, ai0, ar1, ai1;
        load_frags(pl, g, c16, ar0, ai0, ar1, ai1);   // intra-wave: no barrier

        EOut e = fft_core(ar0, ai0, ar1, ai1, fr0, fr1, fi0, fi1, mfi0, mfi1,
                          tw, (_Float16*)&WSP[wv][0], (_Float16*)&WSP[wv][0] + 1280,
                          g, c16);

        __syncthreads();             // all waves done with private planes
#define EMIT(ER, EI, QI, QJ)                                                   \
        _Pragma("unroll")                                                      \
        for (int r = 0; r < 4; ++r) {                                          \
            int k1 = 16 * (QI) + 4 * g + r, k2 = 16 * (QJ) + c16;              \
            h2 p = { (_Float16)ER[r], (_Float16)EI[r] };                       \
            Ttile[k2 * 132 + k1 * 4 + wv] = *(unsigned int*)&p;                \
        }
        EMIT(e.r00, e.i00, 0, 0) EMIT(e.r01, e.i01, 0, 1)
        EMIT(e.r10, e.i10, 1, 0) EMIT(e.r11, e.i11, 1, 1)
#undef EMIT
        __syncthreads();

        // T[nb][k][j]: u32 idx = nb*4096 + k*4 + j. Consecutive t -> +16B.
        #pragma unroll
        for (int jj = 0; jj < 4; ++jj) {
            int k = t + 256 * jj;
            uint4 v = *(uint4*)&Ttile[(k >> 5) * 132 + (k & 31) * 4];
            *(uint4*)&Tw[(size_t)nb * 4096 + (size_t)k * 4] = v;
        }
        __syncthreads();             // WSP reused as stage next iteration
    }
}

// ---------------------------------------------------------------------------
// Pass B: 4 waves/block = 4 columns/iteration, ITER=4 (trig amortized).
// Thread t reads one 64B line (nb=t, 4 consecutive k), scatters to the 4
// wave planes, barrier, per-wave MFMA FFT + modulus from registers.
// ---------------------------------------------------------------------------
__global__ __launch_bounds__(256, 6) void k_colfft(
    const unsigned int* __restrict__ T, _Float16* __restrict__ modb, int wbase)
{
    __shared__ unsigned int WSP[4][1312];
    const int t = threadIdx.x, wv = t >> 6, l = t & 63, g = l >> 4, c16 = l & 15;
    const int wl = blockIdx.y, w = wbase + wl;

    h8 fr0, fi0, fr1, fi1;
    build_ffrags(g, c16, fr0, fi0, fr1, fi1);
    h8 mfi0 = hneg(fi0), mfi1 = hneg(fi1);
    float2 tw[16];
    build_tw(g, c16, tw);

    const unsigned int* Tc = T + (size_t)wl * NPOINTS;
    const int en2 = 4 * (t & 7), en1 = t >> 3;
    const float epsp = 1.09951162778e4f;   // 1e-8 * 2^40

    for (int it = 0; it < ITER; ++it) {
        const int k0 = (blockIdx.x * ITER + it) * 4;
        const int k  = k0 + wv;
        #pragma unroll
        for (int c = 0; c < 4; ++c) {
            uint4 v = *(const uint4*)&Tc[(size_t)t * 4096 + (size_t)(k0 + c) * 4];
            unsigned int* plc = &WSP[c][0];
            plc[PSTR * (en2 + 0) + en1] = v.x;
            plc[PSTR * (en2 + 1) + en1] = v.y;
            plc[PSTR * (en2 + 2) + en1] = v.z;
            plc[PSTR * (en2 + 3) + en1] = v.w;
        }
        __syncthreads();

        h8 ar0, ai0, ar1, ai1;
        load_frags(&WSP[wv][0], g, c16, ar0, ai0, ar1, ai1);

        EOut e = fft_core(ar0, ai0, ar1, ai1, fr0, fr1, fi0, fi1, mfi0, mfi1,
                          tw, (_Float16*)&WSP[wv][0], (_Float16*)&WSP[wv][0] + 1280,
                          g, c16);

        // mod straight from registers: u32 idx = 256*QJ + 16*c16 + 8*QI + 2*g.
        unsigned int* mo = (unsigned int*)(modb + (size_t)w * NPOINTS + (size_t)k * 1024);
#define EMITM(ER, EI, QI, QJ)                                                  \
        {                                                                      \
            float m0 = sqrtf(ER[0]*ER[0] + EI[0]*EI[0] + epsp);                \
            float m1 = sqrtf(ER[1]*ER[1] + EI[1]*EI[1] + epsp);                \
            float m2 = sqrtf(ER[2]*ER[2] + EI[2]*EI[2] + epsp);                \
            float m3 = sqrtf(ER[3]*ER[3] + EI[3]*EI[3] + epsp);                \
            h2 ha = {(_Float16)m0, (_Float16)m1};                              \
            h2 hb = {(_Float16)m2, (_Float16)m3};                              \
            uint2 uv = { *(unsigned int*)&ha, *(unsigned int*)&hb };           \
            *(uint2*)&mo[256 * (QJ) + 16 * c16 + 8 * (QI) + 2 * g] = uv;       \
        }
        EMITM(e.r00, e.i00, 0, 0) EMITM(e.r01, e.i01, 0, 1)
        EMITM(e.r10, e.i10, 1, 0) EMITM(e.r11, e.i11, 1, 1)
#undef EMITM
        __syncthreads();             // WSP reused as stage next iteration
    }
}

// ---------------------------------------------------------------------------
// Pass C: Gram partials via MFMA (validated). 2048 partial rows.
// ---------------------------------------------------------------------------
__global__ __launch_bounds__(256) void k_gram(
    const _Float16* __restrict__ modb, float* __restrict__ part)
{
    __shared__ _Float16 tile[32][520];
    const int t = threadIdx.x;
    const int l = t & 63, wv = t >> 6;
    f32x4 c00 = {0.f,0.f,0.f,0.f}, c01 = {0.f,0.f,0.f,0.f}, c11 = {0.f,0.f,0.f,0.f};
    const size_t pbase = (size_t)blockIdx.x * 2048;

    for (int tt = 0; tt < 4; ++tt) {
        __syncthreads();
        size_t p0 = pbase + (size_t)tt * 512;
        #pragma unroll
        for (int i = 0; i < 8; ++i) {
            int w = i * 4 + wv;
            *(h8*)&tile[w][(size_t)(l * 8)] =
                *(const h8*)&modb[((size_t)w << 20) + p0 + (size_t)(l * 8)];
        }
        __syncthreads();
        #pragma unroll
        for (int s = 0; s < 4; ++s) {
            int k0 = (s * 4 + wv) * 32 + ((l >> 4) * 8);
            h8 a0 = *(const h8*)&tile[l & 15][k0];
            h8 a1 = *(const h8*)&tile[16 + (l & 15)][k0];
            c00 = __builtin_amdgcn_mfma_f32_16x16x32_f16(a0, a0, c00, 0, 0, 0);
            c01 = __builtin_amdgcn_mfma_f32_16x16x32_f16(a0, a1, c01, 0, 0, 0);
            c11 = __builtin_amdgcn_mfma_f32_16x16x32_f16(a1, a1, c11, 0, 0, 0);
        }
    }
    const int row = (blockIdx.x << 2) | wv;
    float* pr = part + ((size_t)row << 10);
    #pragma unroll
    for (int r = 0; r < 4; ++r) {
        int i = (l >> 4) * 4 + r;
        int j = l & 15;
        pr[i * 32 + j]             = c00[r];
        pr[i * 32 + 16 + j]        = c01[r];
        pr[(16 + i) * 32 + 16 + j] = c11[r];
    }
}

// ---------------------------------------------------------------------------
// Pass D: parallel reduce of part[2048][1024]; triangle map; scale 2^-60.
// ---------------------------------------------------------------------------
__global__ __launch_bounds__(256) void k_reduce(
    const float* __restrict__ part, float* __restrict__ out)
{
    __shared__ float red[16][17];
    const int t = threadIdx.x;
    const int sl    = t & 15;
    const int chunk = t >> 4;
    const int slot  = blockIdx.x * 16 + sl;
    float v = 0.0f;
    const int r0 = chunk * 128;
    for (int i = 0; i < 128; ++i)
        v += part[((size_t)(r0 + i) << 10) + slot];
    red[chunk][sl] = v;
    __syncthreads();
    if (t < 16) {
        float s = 0.0f;
        #pragma unroll
        for (int cch = 0; cch < 16; ++cch) s += red[cch][t];
        int sq = blockIdx.x * 16 + t;
        int i = sq >> 5, j = sq & 31;
        if (j >= i) {
            int q = 32 * i - (i * (i - 1)) / 2 + (j - i);
            if (q < 527) out[q] = s * 8.6736173798840355e-19f;   // 2^-60
        }
    }
}

// ---------------------------------------------------------------------------
extern "C" void kernel_launch(void* const* d_in, const int* in_sizes, int n_in,
                              void* d_out, int out_size, void* d_ws, size_t ws_size,
                              hipStream_t stream) {
    (void)in_sizes; (void)n_in; (void)out_size;
    const float*  xhat = (const float*)d_in[0];
    const float*  pre  = (const float*)d_in[1];
    const float*  pim  = (const float*)d_in[2];
    float* out = (float*)d_out;

    char* ws = (char*)d_ws;
    _Float16*     modb = (_Float16*)ws;                              // 64 MB
    float*        part = (float*)(ws + NWV * NPOINTS * 2ULL);        // 8 MB
    size_t        Toff = NWV * NPOINTS * 2ULL + 2048ULL * 1024ULL * 4ULL;
    unsigned int* T    = (unsigned int*)(ws + Toff);                 // WB*4 MB

    // WB=32 preferred: 4 dispatches total, no inter-batch serialization.
    int WB = 1;
    const int cands[6] = {32, 16, 8, 4, 2, 1};
    for (int c = 0; c < 6; ++c)
        if (Toff + (size_t)cands[c] * NPOINTS * 4ULL <= ws_size) { WB = cands[c]; break; }

    for (int wb = 0; wb < NWV; wb += WB) {
        hipLaunchKernelGGL(k_rowfft, dim3(64, WB), dim3(256), 0, stream,
                           xhat, pre, pim, T, wb);
        hipLaunchKernelGGL(k_colfft, dim3(64, WB), dim3(256), 0, stream,
                           (const unsigned int*)T, modb, wb);
    }
    hipLaunchKernelGGL(k_gram, dim3(512), dim3(256), 0, stream,
                       (const _Float16*)modb, part);
    hipLaunchKernelGGL(k_reduce, dim3(64), dim3(256), 0, stream,
                       (const float*)part, out);
}

// Round 12
// 162.855 us; speedup vs baseline: 1.8556x; 1.8556x over previous
//
#include <hip/hip_runtime.h>

// NW=32 wavelets, N=M=1024.
#define NPOINTS 1048576ULL
#define NWV 32
#define ZSTR 40   // h16 stride of [k1][n2] Z planes (16B-aligned rows)
#define PSTR 33   // u32 stride of stage plane [n2][n1] (odd -> <=2-way banks)

typedef _Float16 h8 __attribute__((ext_vector_type(8)));
typedef _Float16 h2 __attribute__((ext_vector_type(2)));
typedef short    s8v __attribute__((ext_vector_type(8)));
typedef float    f32x4 __attribute__((ext_vector_type(4)));

// Scaling plan (rounds 3-11): no 1/(N*M) in the FFTs; conv' = 2^20*conv.
// mod' = sqrt(|conv'|^2 + 1e-8*2^40); final scale 2^-60 in k_reduce.

__device__ __forceinline__ f32x4 MF(h8 a, h8 b, f32x4 c) {
    return __builtin_amdgcn_mfma_f32_16x16x32_f16(a, b, c, 0, 0, 0);
}
__device__ __forceinline__ h8 hneg(h8 x) {
    s8v s = *(s8v*)&x;
    s = s ^ (short)0x8000;
    return *(h8*)&s;
}
// sin/cos of (2*pi*rev): hardware trans ops take REVOLUTIONS (cdna4_isa §3).
__device__ __forceinline__ float fsin_rev(float rev) {
    float r; asm("v_sin_f32 %0, %1" : "=v"(r) : "v"(rev)); return r;
}
__device__ __forceinline__ float fcos_rev(float rev) {
    float r; asm("v_cos_f32 %0, %1" : "=v"(r) : "v"(rev)); return r;
}

// Per-lane F32 fragments (r10-validated; exact dyadic args).
__device__ __forceinline__ void build_ffrags(int g, int c16,
    h8& fr0, h8& fi0, h8& fr1, h8& fi1)
{
    #pragma unroll
    for (int j = 0; j < 8; ++j) {
        int b = 8 * g + j;
        float r0 = (float)((c16 * b) & 31) * (1.0f / 32.0f);
        float r1 = (float)(((16 + c16) * b) & 31) * (1.0f / 32.0f);
        fr0[j] = (_Float16)fcos_rev(r0); fi0[j] = (_Float16)fsin_rev(r0);
        fr1[j] = (_Float16)fcos_rev(r1); fi1[j] = (_Float16)fsin_rev(r1);
    }
}

// Unpack staged u32 (h2{re,im}) plane into MFMA A-fragments.
__device__ __forceinline__ void load_frags(const unsigned int* __restrict__ pl,
    int g, int c16, h8& ar0, h8& ai0, h8& ar1, h8& ai1)
{
    #pragma unroll
    for (int j = 0; j < 8; ++j) {
        unsigned int v0 = pl[PSTR * c16 + 8 * g + j];
        unsigned int v1 = pl[PSTR * (16 + c16) + 8 * g + j];
        h2 p0 = *(h2*)&v0, p1 = *(h2*)&v1;
        ar0[j] = p0.x; ai0[j] = p0.y;
        ar1[j] = p1.x; ai1[j] = p1.y;
    }
}

struct EOut { f32x4 r00, r01, r10, r11, i00, i01, i10, i11; };

// 1024-pt inverse FFT per wave, four-step 32x32 (validated rounds 7-10):
// TW twiddles computed inline via v_sin/v_cos (r10's exact formulas —
// hoisting them to a tw[16] array spilled to scratch in r11; keep inline).
__device__ __forceinline__ EOut fft_core(
    h8 ar0, h8 ai0, h8 ar1, h8 ai1,
    h8 fr0, h8 fr1, h8 fi0, h8 fi1, h8 mfi0, h8 mfi1,
    _Float16* __restrict__ Zr, _Float16* __restrict__ Zi,
    int g, int c16)
{
    const f32x4 z = {0.f, 0.f, 0.f, 0.f};
    f32x4 dr00=z, dr01=z, dr10=z, dr11=z, di00=z, di01=z, di10=z, di11=z;
    dr00 = MF(ar0, fr0, dr00); dr00 = MF(ai0, mfi0, dr00);
    di00 = MF(ar0, fi0, di00); di00 = MF(ai0, fr0,  di00);
    dr01 = MF(ar0, fr1, dr01); dr01 = MF(ai0, mfi1, dr01);
    di01 = MF(ar0, fi1, di01); di01 = MF(ai0, fr1,  di01);
    dr10 = MF(ar1, fr0, dr10); dr10 = MF(ai1, mfi0, dr10);
    di10 = MF(ar1, fi0, di10); di10 = MF(ai1, fr0,  di10);
    dr11 = MF(ar1, fr1, dr11); dr11 = MF(ai1, mfi1, dr11);
    di11 = MF(ar1, fi1, di11); di11 = MF(ai1, fr1,  di11);

#define TWZ(DR, DI, QI, QJ)                                                    \
    {                                                                          \
        const int k1 = 16 * (QJ) + c16;                                        \
        _Pragma("unroll")                                                      \
        for (int rp = 0; rp < 2; ++rp) {                                       \
            const int n2 = 16 * (QI) + 4 * g + 2 * rp;                         \
            float rA = (float)(n2 * k1) * (1.0f / 1024.0f);                    \
            float rB = (float)((n2 + 1) * k1) * (1.0f / 1024.0f);              \
            float2 tA = make_float2(fcos_rev(rA), fsin_rev(rA));               \
            float2 tB = make_float2(fcos_rev(rB), fsin_rev(rB));               \
            float yr0 = DR[2*rp],   yi0 = DI[2*rp];                            \
            float yr1 = DR[2*rp+1], yi1 = DI[2*rp+1];                          \
            h2 zr2 = { (_Float16)(yr0*tA.x - yi0*tA.y),                        \
                       (_Float16)(yr1*tB.x - yi1*tB.y) };                      \
            h2 zi2 = { (_Float16)(yi0*tA.x + yr0*tA.y),                        \
                       (_Float16)(yi1*tB.x + yr1*tB.y) };                      \
            *(h2*)&Zr[k1 * ZSTR + n2] = zr2;                                   \
            *(h2*)&Zi[k1 * ZSTR + n2] = zi2;                                   \
        }                                                                      \
    }
    TWZ(dr00, di00, 0, 0) TWZ(dr01, di01, 0, 1)
    TWZ(dr10, di10, 1, 0) TWZ(dr11, di11, 1, 1)
#undef TWZ

    h8 a3r0 = *(h8*)&Zr[c16 * ZSTR + 8 * g];
    h8 a3i0 = *(h8*)&Zi[c16 * ZSTR + 8 * g];
    h8 a3r1 = *(h8*)&Zr[(16 + c16) * ZSTR + 8 * g];
    h8 a3i1 = *(h8*)&Zi[(16 + c16) * ZSTR + 8 * g];

    EOut e;
    e.r00 = MF(a3r0, fr0, z); e.r00 = MF(a3i0, mfi0, e.r00);
    e.i00 = MF(a3r0, fi0, z); e.i00 = MF(a3i0, fr0,  e.i00);
    e.r01 = MF(a3r0, fr1, z); e.r01 = MF(a3i0, mfi1, e.r01);
    e.i01 = MF(a3r0, fi1, z); e.i01 = MF(a3i0, fr1,  e.i01);
    e.r10 = MF(a3r1, fr0, z); e.r10 = MF(a3i1, mfi0, e.r10);
    e.i10 = MF(a3r1, fi0, z); e.i10 = MF(a3i1, fr0,  e.i10);
    e.r11 = MF(a3r1, fr1, z); e.r11 = MF(a3i1, mfi1, e.r11);
    e.i11 = MF(a3r1, fi1, z); e.i11 = MF(a3i1, fr1,  e.i11);
    return e;
}

// ---------------------------------------------------------------------------
// Pass A: 4 waves/block = 4 rows of one wavelet (r10 structure). ALL 16
// dwordx4 loads issued into registers FIRST (full MLP; needs the (256,4)
// VGPR cap=128 — (256,6)'s 85 forced load serialization), then cmul+stage,
// MFMA FFT, block transpose, coalesced stores to T[nb][k][4n].
// ---------------------------------------------------------------------------
__global__ __launch_bounds__(256, 4) void k_rowfft(
    const float* __restrict__ xhat, const float* __restrict__ pre,
    const float* __restrict__ pim, unsigned int* __restrict__ T, int wbase)
{
    __shared__ unsigned int WSP[4][1312];   // per-wave stage/Z union; Ttile union
    const int t = threadIdx.x, wv = t >> 6, l = t & 63, g = l >> 4, c16 = l & 15;
    const int nb = blockIdx.x, n = nb * 4 + wv;
    const int wl = blockIdx.y, w = wbase + wl;

    // Issue ALL global loads first (16 x 16B in flight).
    const float4* pr4 = (const float4*)(pre + (size_t)w * NPOINTS + (size_t)n * 1024);
    const float4* pi4 = (const float4*)(pim + (size_t)w * NPOINTS + (size_t)n * 1024);
    const float4* xh4 = (const float4*)(xhat + (size_t)n * 2048);
    float4 A0 = pr4[l],        A1 = pr4[64 + l],     A2 = pr4[128 + l],     A3 = pr4[192 + l];
    float4 B0 = pi4[l],        B1 = pi4[64 + l],     B2 = pi4[128 + l],     B3 = pi4[192 + l];
    float4 Xa0 = xh4[2*l],     Xb0 = xh4[2*l + 1];
    float4 Xa1 = xh4[128 + 2*l], Xb1 = xh4[128 + 2*l + 1];
    float4 Xa2 = xh4[256 + 2*l], Xb2 = xh4[256 + 2*l + 1];
    float4 Xa3 = xh4[384 + 2*l], Xb3 = xh4[384 + 2*l + 1];

    h8 fr0, fi0, fr1, fi1;
    build_ffrags(g, c16, fr0, fi0, fr1, fi1);   // trans-ops overlap load latency
    h8 mfi0 = hneg(fi0), mfi1 = hneg(fi1);

    // Stage: m = 256c + 4l + i  ->  n1 = 8c + (l>>3), n2 = 4*(l&7) + i.
    unsigned int* pl = &WSP[wv][0];
    const int n2b = 4 * (l & 7), n1b = l >> 3;
#define STAGE(C, A, B, XA, XB)                                                 \
    {                                                                          \
        float xr[4] = {XA.x, XA.z, XB.x, XB.z};                                \
        float xi[4] = {XA.y, XA.w, XB.y, XB.w};                                \
        float pa[4] = {A.x, A.y, A.z, A.w};                                    \
        float pb[4] = {B.x, B.y, B.z, B.w};                                    \
        const int n1 = 8 * (C) + n1b;                                          \
        _Pragma("unroll")                                                      \
        for (int i = 0; i < 4; ++i) {                                          \
            float re = xr[i] * pa[i] - xi[i] * pb[i];                          \
            float im = xi[i] * pa[i] + xr[i] * pb[i];                          \
            h2 p = {(_Float16)re, (_Float16)im};                               \
            pl[PSTR * (n2b + i) + n1] = *(unsigned int*)&p;                    \
        }                                                                      \
    }
    STAGE(0, A0, B0, Xa0, Xb0) STAGE(1, A1, B1, Xa1, Xb1)
    STAGE(2, A2, B2, Xa2, Xb2) STAGE(3, A3, B3, Xa3, Xb3)
#undef STAGE

    h8 ar0, ai0, ar1, ai1;
    load_frags(pl, g, c16, ar0, ai0, ar1, ai1);   // intra-wave: no barrier

    EOut e = fft_core(ar0, ai0, ar1, ai1, fr0, fr1, fi0, fi1, mfi0, mfi1,
                      (_Float16*)&WSP[wv][0], (_Float16*)&WSP[wv][0] + 1280,
                      g, c16);

    __syncthreads();                 // all waves done with private planes
    unsigned int* Ttile = &WSP[0][0];       // [k2]*132 + [k1]*4 + wv
#define EMIT(ER, EI, QI, QJ)                                                   \
    _Pragma("unroll")                                                          \
    for (int r = 0; r < 4; ++r) {                                              \
        int k1 = 16 * (QI) + 4 * g + r, k2 = 16 * (QJ) + c16;                  \
        h2 p = { (_Float16)ER[r], (_Float16)EI[r] };                           \
        Ttile[k2 * 132 + k1 * 4 + wv] = *(unsigned int*)&p;                    \
    }
    EMIT(e.r00, e.i00, 0, 0) EMIT(e.r01, e.i01, 0, 1)
    EMIT(e.r10, e.i10, 1, 0) EMIT(e.r11, e.i11, 1, 1)
#undef EMIT
    __syncthreads();

    // T[nb][k][j]: u32 idx = nb*4096 + k*4 + j. Consecutive t -> +16B.
    unsigned int* Tw = T + (size_t)wl * NPOINTS;
    #pragma unroll
    for (int jj = 0; jj < 4; ++jj) {
        int k = t + 256 * jj;
        uint4 v = *(uint4*)&Ttile[(k >> 5) * 132 + (k & 31) * 4];
        *(uint4*)&Tw[(size_t)nb * 4096 + (size_t)k * 4] = v;
    }
}

// ---------------------------------------------------------------------------
// Pass B: 4 waves/block = 4 consecutive columns (r10 structure). All 4 line
// loads issued first, scatter to wave planes, one barrier, MFMA FFT,
// modulus straight from registers (coalesced uint2 stores).
// ---------------------------------------------------------------------------
__global__ __launch_bounds__(256, 4) void k_colfft(
    const unsigned int* __restrict__ T, _Float16* __restrict__ modb, int wbase)
{
    __shared__ unsigned int WSP[4][1312];
    const int t = threadIdx.x, wv = t >> 6, l = t & 63, g = l >> 4, c16 = l & 15;
    const int k0 = blockIdx.x * 4, k = k0 + wv;
    const int wl = blockIdx.y, w = wbase + wl;

    // Issue all 4 uint4 loads first (one full 64B line per thread).
    const unsigned int* Tc = T + (size_t)wl * NPOINTS;
    uint4 v0 = *(const uint4*)&Tc[(size_t)t * 4096 + (size_t)(k0 + 0) * 4];
    uint4 v1 = *(const uint4*)&Tc[(size_t)t * 4096 + (size_t)(k0 + 1) * 4];
    uint4 v2 = *(const uint4*)&Tc[(size_t)t * 4096 + (size_t)(k0 + 2) * 4];
    uint4 v3 = *(const uint4*)&Tc[(size_t)t * 4096 + (size_t)(k0 + 3) * 4];

    h8 fr0, fi0, fr1, fi1;
    build_ffrags(g, c16, fr0, fi0, fr1, fi1);
    h8 mfi0 = hneg(fi0), mfi1 = hneg(fi1);

    const int en2 = 4 * (t & 7), en1 = t >> 3;
#define SCAT(C, V)                                                             \
    {                                                                          \
        unsigned int* plc = &WSP[C][0];                                        \
        plc[PSTR * (en2 + 0) + en1] = V.x;                                     \
        plc[PSTR * (en2 + 1) + en1] = V.y;                                     \
        plc[PSTR * (en2 + 2) + en1] = V.z;                                     \
        plc[PSTR * (en2 + 3) + en1] = V.w;                                     \
    }
    SCAT(0, v0) SCAT(1, v1) SCAT(2, v2) SCAT(3, v3)
#undef SCAT
    __syncthreads();

    h8 ar0, ai0, ar1, ai1;
    load_frags(&WSP[wv][0], g, c16, ar0, ai0, ar1, ai1);

    EOut e = fft_core(ar0, ai0, ar1, ai1, fr0, fr1, fi0, fi1, mfi0, mfi1,
                      (_Float16*)&WSP[wv][0], (_Float16*)&WSP[wv][0] + 1280,
                      g, c16);

    // mod straight from registers: u32 idx = 256*QJ + 16*c16 + 8*QI + 2*g + rp.
    unsigned int* mo = (unsigned int*)(modb + (size_t)w * NPOINTS + (size_t)k * 1024);
    const float epsp = 1.09951162778e4f;   // 1e-8 * 2^40
#define EMITM(ER, EI, QI, QJ)                                                  \
    {                                                                          \
        float m0 = sqrtf(ER[0]*ER[0] + EI[0]*EI[0] + epsp);                    \
        float m1 = sqrtf(ER[1]*ER[1] + EI[1]*EI[1] + epsp);                    \
        float m2 = sqrtf(ER[2]*ER[2] + EI[2]*EI[2] + epsp);                    \
        float m3 = sqrtf(ER[3]*ER[3] + EI[3]*EI[3] + epsp);                    \
        h2 ha = {(_Float16)m0, (_Float16)m1};                                  \
        h2 hb = {(_Float16)m2, (_Float16)m3};                                  \
        uint2 uv = { *(unsigned int*)&ha, *(unsigned int*)&hb };               \
        *(uint2*)&mo[256 * (QJ) + 16 * c16 + 8 * (QI) + 2 * g] = uv;           \
    }
    EMITM(e.r00, e.i00, 0, 0) EMITM(e.r01, e.i01, 0, 1)
    EMITM(e.r10, e.i10, 1, 0) EMITM(e.r11, e.i11, 1, 1)
#undef EMITM
}

// ---------------------------------------------------------------------------
// Pass C: Gram partials via MFMA (validated). 2048 partial rows.
// ---------------------------------------------------------------------------
__global__ __launch_bounds__(256) void k_gram(
    const _Float16* __restrict__ modb, float* __restrict__ part)
{
    __shared__ _Float16 tile[32][520];
    const int t = threadIdx.x;
    const int l = t & 63, wv = t >> 6;
    f32x4 c00 = {0.f,0.f,0.f,0.f}, c01 = {0.f,0.f,0.f,0.f}, c11 = {0.f,0.f,0.f,0.f};
    const size_t pbase = (size_t)blockIdx.x * 2048;

    for (int tt = 0; tt < 4; ++tt) {
        __syncthreads();
        size_t p0 = pbase + (size_t)tt * 512;
        #pragma unroll
        for (int i = 0; i < 8; ++i) {
            int w = i * 4 + wv;
            *(h8*)&tile[w][(size_t)(l * 8)] =
                *(const h8*)&modb[((size_t)w << 20) + p0 + (size_t)(l * 8)];
        }
        __syncthreads();
        #pragma unroll
        for (int s = 0; s < 4; ++s) {
            int k0 = (s * 4 + wv) * 32 + ((l >> 4) * 8);
            h8 a0 = *(const h8*)&tile[l & 15][k0];
            h8 a1 = *(const h8*)&tile[16 + (l & 15)][k0];
            c00 = __builtin_amdgcn_mfma_f32_16x16x32_f16(a0, a0, c00, 0, 0, 0);
            c01 = __builtin_amdgcn_mfma_f32_16x16x32_f16(a0, a1, c01, 0, 0, 0);
            c11 = __builtin_amdgcn_mfma_f32_16x16x32_f16(a1, a1, c11, 0, 0, 0);
        }
    }
    const int row = (blockIdx.x << 2) | wv;
    float* pr = part + ((size_t)row << 10);
    #pragma unroll
    for (int r = 0; r < 4; ++r) {
        int i = (l >> 4) * 4 + r;
        int j = l & 15;
        pr[i * 32 + j]             = c00[r];
        pr[i * 32 + 16 + j]        = c01[r];
        pr[(16 + i) * 32 + 16 + j] = c11[r];
    }
}

// ---------------------------------------------------------------------------
// Pass D: parallel reduce of part[2048][1024]; triangle map; scale 2^-60.
// ---------------------------------------------------------------------------
__global__ __launch_bounds__(256) void k_reduce(
    const float* __restrict__ part, float* __restrict__ out)
{
    __shared__ float red[16][17];
    const int t = threadIdx.x;
    const int sl    = t & 15;
    const int chunk = t >> 4;
    const int slot  = blockIdx.x * 16 + sl;
    float v = 0.0f;
    const int r0 = chunk * 128;
    for (int i = 0; i < 128; ++i)
        v += part[((size_t)(r0 + i) << 10) + slot];
    red[chunk][sl] = v;
    __syncthreads();
    if (t < 16) {
        float s = 0.0f;
        #pragma unroll
        for (int cch = 0; cch < 16; ++cch) s += red[cch][t];
        int sq = blockIdx.x * 16 + t;
        int i = sq >> 5, j = sq & 31;
        if (j >= i) {
            int q = 32 * i - (i * (i - 1)) / 2 + (j - i);
            if (q < 527) out[q] = s * 8.6736173798840355e-19f;   // 2^-60
        }
    }
}

// ---------------------------------------------------------------------------
extern "C" void kernel_launch(void* const* d_in, const int* in_sizes, int n_in,
                              void* d_out, int out_size, void* d_ws, size_t ws_size,
                              hipStream_t stream) {
    (void)in_sizes; (void)n_in; (void)out_size;
    const float*  xhat = (const float*)d_in[0];
    const float*  pre  = (const float*)d_in[1];
    const float*  pim  = (const float*)d_in[2];
    float* out = (float*)d_out;

    char* ws = (char*)d_ws;
    _Float16*     modb = (_Float16*)ws;                              // 64 MB
    float*        part = (float*)(ws + NWV * NPOINTS * 2ULL);        // 8 MB
    size_t        Toff = NWV * NPOINTS * 2ULL + 2048ULL * 1024ULL * 4ULL;
    unsigned int* T    = (unsigned int*)(ws + Toff);                 // WB*4 MB

    // WB=32 preferred: 4 dispatches total, no inter-batch serialization.
    int WB = 1;
    const int cands[6] = {32, 16, 8, 4, 2, 1};
    for (int c = 0; c < 6; ++c)
        if (Toff + (size_t)cands[c] * NPOINTS * 4ULL <= ws_size) { WB = cands[c]; break; }

    for (int wb = 0; wb < NWV; wb += WB) {
        hipLaunchKernelGGL(k_rowfft, dim3(256, WB), dim3(256), 0, stream,
                           xhat, pre, pim, T, wb);
        hipLaunchKernelGGL(k_colfft, dim3(256, WB), dim3(256), 0, stream,
                           (const unsigned int*)T, modb, wb);
    }
    hipLaunchKernelGGL(k_gram, dim3(512), dim3(256), 0, stream,
                       (const _Float16*)modb, part);
    hipLaunchKernelGGL(k_reduce, dim3(64), dim3(256), 0, stream,
                       (const float*)part, out);
}